// Round 9
// baseline (161.843 us; speedup 1.0000x reference)
//
#include <hip/hip_runtime.h>
#include <hip/hip_bf16.h>
#include <hip/hip_fp8.h>

// ContrastiveLoss (SimCLR InfoNCE): N=8192, D=1024, T=0.1
// nll[i] = -logit[i, (i+N/2)%N] + logsumexp_j(logit[i,j]), diag masked out
// logit = cos_sim / T; out = mean(nll)
//
// Identities:
//  - zn_i = z_i * sqrt(10*log2e)/||z_i||  =>  dot d = logit*log2e and
//    exp(logit-10) = 2^(d - 10*log2e) -> raw v_exp_f32.
//  - logit in [-10,10] => FIXED-offset logsumexp; masked diag term == 0.
//  - Gram symmetric: upper-tri 128x128 supertiles (2080); off-diag tile
//    (I,J) adds exp row-sums to rows of I, col-sums to rows of J.
//  - positive-pair logits = tile diagonals of supertiles (I, I+32).
//  - MX-scaled fp8 K=128 MFMA with all scales = 1.0 (2x bf16 rate).
//
// R21: B operand DIRECT from global/L2 to registers; only A staged in LDS.
// Evidence: R17's 2077cy/CU phase wall decomposes as DS-pipe ~85% busy
// (192KB frag reads @256B/cy + 96KB DMA writes @128B/cy + conflicts) with
// 2 barriers/phase aligning 12 waves on the DMA drain; MfmaUtil arithmetic
// (3 waves/SIMD x 152cy MFMA / 2077) = 22% matches the counter. R20 (256^2)
// spilled (3rd reg-budget casualty) - discarded. Direct-B works because the
// lane's B fragment is a CONTIGUOUS 32B of the zn row: global chunk pair
// (quad*2, quad*2+1) at (colBase+r)*1024 + quad*32 (the LDS XOR-swizzle
// algebra cancels); supercell order keeps panels L2-hot (R17: FETCH 23MB
// vs 532MB panel reads = 96% hit); lo/hi 16B pair in the same cachelines
// so L1 absorbs the 2x touch and cross-wave duplication. Effect: DS reads
// halve, DMA writes halve, barrier2 DELETED (one __syncthreads/phase),
// +8 VGPR only (156 <= 170 -> still 3 blocks/CU). LDS 34KB. Predicted:
// gemm 56->44-48us, MfmaUtil ~30%, conflicts >=2x down, WRITE ~19MB
// (VGPR ~92, no spill). If neutral w/ flat MfmaUtil: TA gather rate is
// the wall -> B back to LDS + st_16x32 swizzle next.

#define N_ROWS 8192
#define DIM    1024
#define BM 128
#define BK 128                         // bytes (= elems) of K per phase
#define NPHASE (DIM / BK)              // 8
#define NT     (N_ROWS / BM)           // 64
#define NTILES (NT * (NT + 1) / 2)     // 2080
#define OFFS   14.4269504088896340f    // 10 * log2e
#define ROW_SCALE 3.7982825605f        // sqrt(10 * log2e)
#define LN2    0.6931471805599453f
#define LOGIT_MAX 10.0f
#define SCALE1 0x7F7F7F7F              // e8m0 1.0 in every byte

typedef float floatx4 __attribute__((ext_vector_type(4)));
typedef int   intx4   __attribute__((ext_vector_type(4)));
typedef int   intx8   __attribute__((ext_vector_type(8)));

__device__ __forceinline__ void async_copy16(const void* g, void* lds) {
  __builtin_amdgcn_global_load_lds(
      (const __attribute__((address_space(1))) void*)g,
      (__attribute__((address_space(3))) void*)lds, 16, 0, 0);
}

__device__ __forceinline__ unsigned pack4_e4m3(float a, float b, float c, float d) {
  __hip_fp8_e4m3 qa(a), qb(b), qc(c), qd(d);
  return (unsigned)qa.__x | ((unsigned)qb.__x << 8) |
         ((unsigned)qc.__x << 16) | ((unsigned)qd.__x << 24);
}

// ---------------- Kernel 1: row normalize -> fp8 (+ zero accumulators) ----
__global__ __launch_bounds__(256) void normalize_kernel(
    const float* __restrict__ z, unsigned char* __restrict__ zn,
    float* __restrict__ sumexp, float* __restrict__ out) {
  const int tid = threadIdx.x, wave = tid >> 6, lane = tid & 63;
  const int row = blockIdx.x * 4 + wave;

  if (blockIdx.x < 8) ((float4*)sumexp)[blockIdx.x * 256 + tid] = float4{0, 0, 0, 0};
  if (blockIdx.x == 8 && tid == 0) out[0] = 0.0f;

  const float4* zr = (const float4*)(z + (size_t)row * DIM);
  float4 v[4];
  #pragma unroll
  for (int j = 0; j < 4; j++) v[j] = zr[lane + 64 * j];
  float ss = 0.0f;
  #pragma unroll
  for (int j = 0; j < 4; j++)
    ss += v[j].x * v[j].x + v[j].y * v[j].y + v[j].z * v[j].z + v[j].w * v[j].w;
  #pragma unroll
  for (int off = 32; off > 0; off >>= 1) ss += __shfl_xor(ss, off);
  const float scale = rsqrtf(ss) * ROW_SCALE;  // norms ~32 >> eps

  unsigned* o = (unsigned*)(zn + (size_t)row * DIM);
  #pragma unroll
  for (int j = 0; j < 4; j++)
    o[lane + 64 * j] = pack4_e4m3(v[j].x * scale, v[j].y * scale,
                                  v[j].z * scale, v[j].w * scale);
}

// Supercell-major tile decode: 64x64 upper-tri grid partitioned into 8x8
// supercells (rows SI, cols SJ >= SI). Diag cell = 36 tiles, off-diag = 64.
// Prefix P(SI) = 516*SI - 32*SI*SI (P(8)=2080). Within a cell-row: diag
// cell first, then snake over off-diag cells; within cell row-major.
// Confirmed R17: FETCH 66->23MB, gemm 65.3->56.4us.
__device__ __forceinline__ void decode_tile(int g, int& I, int& J) {
  int SI = 0;
  #pragma unroll
  for (int s = 1; s < 8; ++s)
    if (516 * s - 32 * s * s <= g) SI = s;
  int rem = g - (516 * SI - 32 * SI * SI);
  int i, j, SJ;
  if (rem < 36) {                       // diagonal supercell, upper-tri 8x8
    SJ = SI;
    i = 0;
    while ((i + 1) * (17 - (i + 1)) / 2 <= rem) ++i;  // prefix(i)=i*(17-i)/2
    j = i + (rem - i * (17 - i) / 2);
  } else {                              // full off-diagonal supercell
    const int rem2 = rem - 36;
    const int cc = rem2 >> 6;           // 0 .. (6-SI)
    const int k  = rem2 & 63;
    SJ = (SI & 1) ? (7 - cc) : (SI + 1 + cc);
    i = k >> 3;
    j = k & 7;
  }
  I = SI * 8 + i;
  J = SJ * 8 + j;
}

// ---------------- Kernel 2: upper-tri MX-fp8 GEMM + partial sum-exp -------
__global__ __launch_bounds__(256, 3) void fused_gemm_lse(
    const unsigned char* __restrict__ zn, float* __restrict__ sumexp,
    float* __restrict__ pos) {
  __shared__ unsigned char sA[2][BM * BK];    // 2 x 16 KB (double buffer)
  __shared__ float rowRed[2][BM];             // 1 KB
  __shared__ float colRed[2][BM];             // 1 KB   (total 34 KB)

  const int tid  = threadIdx.x;
  const int lane = tid & 63;
  const int wave = tid >> 6;
  const int quad = lane >> 4;
  const int l15  = lane & 15;
  const int waveM = wave >> 1;  // 0..1
  const int waveN = wave & 1;   // 0..1

  // XCD-contiguous tile permutation (2080 = 8 * 260)
  const int t = (blockIdx.x & 7) * (NTILES / 8) + (blockIdx.x >> 3);
  int I, J;
  decode_tile(t, I, J);
  const int rowBase = I * BM, colBase = J * BM;

  // A staging: 128x128B tile = 1024 16B-chunks, 4/thread.
  // chunk s: row r = s>>3, stored slot s&7 holds logical 16B k-chunk
  // q = (s&7) ^ (r&7)  (XOR swizzle, applied on the global-address side).
  const unsigned char* aP[4];
  int soff[4];
  #pragma unroll
  for (int i = 0; i < 4; i++) {
    const int s = i * 256 + tid;            // i*256 + wave*64 + lane
    const int r = s >> 3;                   // tile row 0..127
    const int q = (s & 7) ^ (r & 7);        // logical k-chunk 0..7
    aP[i] = zn + (size_t)(rowBase + r) * DIM + q * 16;
    soff[i] = s * 16;                       // wave-uniform base + lane*16
  }
  auto stageA = [&](int b) {
    #pragma unroll
    for (int i = 0; i < 4; i++) {
      async_copy16(aP[i], (char*)sA[b] + soff[i]);
      aP[i] += BK;
    }
  };

  // B direct-from-global: lane (quad,l15) of wave (waveN) needs, for frag
  // ni at phase p, the contiguous 32B  zn[colBase + waveN*64+ni*16+l15]
  // [p*128 + quad*32 .. +32). lo = first 16B, hi = second (k-chunks
  // quad*2, quad*2+1 -- the swizzle algebra cancels for direct loads).
  const unsigned char* bQ[4];
  #pragma unroll
  for (int ni = 0; ni < 4; ni++) {
    const int r = waveN * 64 + ni * 16 + l15;
    bQ[ni] = zn + (size_t)(colBase + r) * DIM + quad * 32;
  }

  floatx4 acc[4][4];
  #pragma unroll
  for (int mi = 0; mi < 4; mi++)
    #pragma unroll
    for (int ni = 0; ni < 4; ni++) acc[mi][ni] = {0.f, 0.f, 0.f, 0.f};

  stageA(0);

  for (int p = 0; p < NPHASE; ++p) {
    const int b = p & 1;
    __syncthreads();                 // A[p] staged (vmcnt drained), prev reads done
    if (p + 1 < NPHASE) stageA(b ^ 1);   // async prefetch of A[p+1]

    // B fragments straight from L2 (panels hot via supercell order)
    intx8 bb[4];
    #pragma unroll
    for (int ni = 0; ni < 4; ni++) {
      const intx4 lo = *(const intx4*)(bQ[ni] + p * BK);
      const intx4 hi = *(const intx4*)(bQ[ni] + p * BK + 16);
      bb[ni] = __builtin_shufflevector(lo, hi, 0, 1, 2, 3, 4, 5, 6, 7);
    }

    #pragma unroll
    for (int mi = 0; mi < 4; mi++) {
      const int r = waveM * 64 + mi * 16 + l15;
      const int c0 = (quad * 2) ^ (r & 7);
      const intx4 lo = *(const intx4*)(&sA[b][0] + (r * 8 + c0) * 16);
      const intx4 hi = *(const intx4*)(&sA[b][0] + (r * 8 + (c0 ^ 1)) * 16);
      const intx8 a = __builtin_shufflevector(lo, hi, 0, 1, 2, 3, 4, 5, 6, 7);
      #pragma unroll
      for (int ni = 0; ni < 4; ni++)
        acc[mi][ni] = __builtin_amdgcn_mfma_scale_f32_16x16x128_f8f6f4(
            a, bb[ni], acc[mi][ni],
            0 /*cbsz: A=e4m3*/, 0 /*blgp: B=e4m3*/,
            0, SCALE1,   // opsel_a, scale_a = 1.0
            0, SCALE1);  // opsel_b, scale_b = 1.0
    }
  }

  // ---- epilogue ----
  // C/D layout (16x16 shape family): col = lane&15, row = quad*4 + reg
  const bool diagBlk = (I == J);

  if (J == I + 32 && waveM == waveN) {  // positive-pair supertile
    #pragma unroll
    for (int mi = 0; mi < 4; mi++)
      #pragma unroll
      for (int r = 0; r < 4; r++)
        if (l15 == quad * 4 + r)
          pos[rowBase + waveM * 64 + mi * 16 + l15] = acc[mi][mi][r];
  }

  float rsum[4][4], csum[4];
  #pragma unroll
  for (int mi = 0; mi < 4; mi++)
    #pragma unroll
    for (int r = 0; r < 4; r++) rsum[mi][r] = 0.0f;
  #pragma unroll
  for (int ni = 0; ni < 4; ni++) csum[ni] = 0.0f;

  if (diagBlk) {
    #pragma unroll
    for (int mi = 0; mi < 4; mi++)
      #pragma unroll
      for (int ni = 0; ni < 4; ni++) {
        const bool dtile = (waveM == waveN) && (mi == ni);
        #pragma unroll
        for (int r = 0; r < 4; r++) {
          float e = exp2f(acc[mi][ni][r] - OFFS);
          if (dtile && l15 == quad * 4 + r) e = 0.0f;  // masked diagonal
          rsum[mi][r] += e;
        }
      }
  } else {
    #pragma unroll
    for (int mi = 0; mi < 4; mi++)
      #pragma unroll
      for (int ni = 0; ni < 4; ni++)
        #pragma unroll
        for (int r = 0; r < 4; r++) {
          const float e = exp2f(acc[mi][ni][r] - OFFS);
          rsum[mi][r] += e;
          csum[ni]    += e;
        }
  }

  #pragma unroll
  for (int mi = 0; mi < 4; mi++)
    #pragma unroll
    for (int r = 0; r < 4; r++) {
      float v = rsum[mi][r];
      v += __shfl_xor(v, 1);
      v += __shfl_xor(v, 2);
      v += __shfl_xor(v, 4);
      v += __shfl_xor(v, 8);
      if (l15 == 0)
        rowRed[waveN][waveM * 64 + mi * 16 + quad * 4 + r] = v;
    }
  if (!diagBlk) {
    #pragma unroll
    for (int ni = 0; ni < 4; ni++) {
      float v = csum[ni];
      v += __shfl_xor(v, 16);
      v += __shfl_xor(v, 32);
      if (quad == 0)
        colRed[waveM][waveN * 64 + ni * 16 + l15] = v;
    }
  }
  __syncthreads();

  if (tid < BM) {
    atomicAdd(&sumexp[rowBase + tid], rowRed[0][tid] + rowRed[1][tid]);
  } else if (!diagBlk) {
    const int c = tid - BM;
    atomicAdd(&sumexp[colBase + c], colRed[0][c] + colRed[1][c]);
  }
}

// ---------------- Kernel 3: mean NLL --------------------------------------
__global__ __launch_bounds__(256) void finalize_kernel(
    const float* __restrict__ sumexp, const float* __restrict__ pos,
    float* __restrict__ out) {
  const int tid = threadIdx.x;
  const int row = blockIdx.x * 256 + tid;
  // pos holds d = logit*log2e for rows [0,4096); pos[i+4096] == pos[i]
  float local = -(pos[row & (N_ROWS / 2 - 1)] * LN2) + LOGIT_MAX + logf(sumexp[row]);
  #pragma unroll
  for (int off = 32; off > 0; off >>= 1) local += __shfl_xor(local, off);
  __shared__ float red[4];
  const int wave = tid >> 6, lane = tid & 63;
  if (lane == 0) red[wave] = local;
  __syncthreads();
  if (tid == 0)
    atomicAdd(out, (red[0] + red[1] + red[2] + red[3]) * (1.0f / N_ROWS));
}

extern "C" void kernel_launch(void* const* d_in, const int* in_sizes, int n_in,
                              void* d_out, int out_size, void* d_ws, size_t ws_size,
                              hipStream_t stream) {
  const float* z = (const float*)d_in[0];
  float* out = (float*)d_out;

  char* ws = (char*)d_ws;
  unsigned char* zn = (unsigned char*)ws;                    // 8 MB fp8
  float* sumexp = (float*)(ws + (size_t)N_ROWS * DIM);       // 32 KB
  float* pos    = sumexp + N_ROWS;                           // 16 KB

  normalize_kernel<<<N_ROWS / 4, 256, 0, stream>>>(z, zn, sumexp, out);
  fused_gemm_lse<<<NTILES, 256, 0, stream>>>(zn, sumexp, pos);
  finalize_kernel<<<N_ROWS / 256, 256, 0, stream>>>(sumexp, pos, out);
}

// Round 10
// 136.374 us; speedup vs baseline: 1.1868x; 1.1868x over previous
//
#include <hip/hip_runtime.h>
#include <hip/hip_bf16.h>
#include <hip/hip_fp8.h>

// ContrastiveLoss (SimCLR InfoNCE): N=8192, D=1024, T=0.1
// nll[i] = -logit[i, (i+N/2)%N] + logsumexp_j(logit[i,j]), diag masked out
// logit = cos_sim / T; out = mean(nll)
//
// Identities:
//  - zn_i = z_i * sqrt(10*log2e)/||z_i||  =>  dot d = logit*log2e and
//    exp(logit-10) = 2^(d - 10*log2e) -> raw v_exp_f32.
//  - logit in [-10,10] => FIXED-offset logsumexp; masked diag term == 0.
//  - Gram symmetric: upper-tri 256x256 supertiles (528); off-diag tile
//    (I,J) adds exp row-sums to rows of I, col-sums to rows of J. Diag
//    supertile: compute full square, rsum only (lower half supplies the
//    mirrored col contributions), mask true diagonal.
//  - positive-pair logits: J == I+16 supertiles, local col == local row.
//  - MX-scaled fp8 K=128 MFMA with all scales = 1.0 (2x bf16 rate).
//
// R22: 256^2 tile / 8 waves / wave=64x128 / ONE barrier per phase.
// Evidence chain: R17 (56.4us) is the floor of the 64x64-wave space --
// 8 variants bracketed it; only bytes-per-output ever moved time. Wave
// m*n costs (m+n)*BK LDS-bytes per m*n outputs: 64x64 = 4B/out ->
// 64x128 = 3B/out (-25% DS traffic), and 256^2 tiles halve global
// staged bytes (532->270MB) + 4x fewer epilogues. R21 proved B must
// stay in LDS (direct-global gather = 92us). R20's spill re-derived:
// launch_bounds(512,2) let the allocator target 128 VGPR (4 waves/EU)
// and spill the 128-AGPR acc; fix = launch_bounds(512,1) (cap 256) +
// lean live-set: HOLD A (4 frags, 32 regs), STREAM B (8 regs at a
// time) -> peak ~190 regs. Full A+B dbuf (134KB LDS, fits: R20 ran
// this size) -> no barrier2; __syncthreads drains the single
// outstanding stage batch (R17 cadence). Supercell 4x4 order + XOR
// swizzle + epilogue algebra carried from R20 (correctness-verified).
// Predicted: gemm -> 38-44us, MfmaUtil 35-45%, WRITE ~18.6MB &
// VGPR >= ~160 (spill check: VGPR=128/WRITE~30MB = allocator lost).

#define N_ROWS 8192
#define DIM    1024
#define BM 256                         // supertile edge
#define BK 128                         // bytes (= elems) of K per phase
#define NPHASE (DIM / BK)              // 8
#define NT     (N_ROWS / BM)           // 32
#define NTILES (NT * (NT + 1) / 2)     // 528 = 8 * 66
#define OFFS   14.4269504088896340f    // 10 * log2e
#define ROW_SCALE 3.7982825605f        // sqrt(10 * log2e)
#define LN2    0.6931471805599453f
#define LOGIT_MAX 10.0f
#define SCALE1 0x7F7F7F7F              // e8m0 1.0 in every byte

typedef float floatx4 __attribute__((ext_vector_type(4)));
typedef int   intx4   __attribute__((ext_vector_type(4)));
typedef int   intx8   __attribute__((ext_vector_type(8)));

__device__ __forceinline__ void async_copy16(const void* g, void* lds) {
  __builtin_amdgcn_global_load_lds(
      (const __attribute__((address_space(1))) void*)g,
      (__attribute__((address_space(3))) void*)lds, 16, 0, 0);
}

__device__ __forceinline__ unsigned pack4_e4m3(float a, float b, float c, float d) {
  __hip_fp8_e4m3 qa(a), qb(b), qc(c), qd(d);
  return (unsigned)qa.__x | ((unsigned)qb.__x << 8) |
         ((unsigned)qc.__x << 16) | ((unsigned)qd.__x << 24);
}

// ---------------- Kernel 1: row normalize -> fp8 (+ zero accumulators) ----
__global__ __launch_bounds__(256) void normalize_kernel(
    const float* __restrict__ z, unsigned char* __restrict__ zn,
    float* __restrict__ sumexp, float* __restrict__ out) {
  const int tid = threadIdx.x, wave = tid >> 6, lane = tid & 63;
  const int row = blockIdx.x * 4 + wave;

  if (blockIdx.x < 8) ((float4*)sumexp)[blockIdx.x * 256 + tid] = float4{0, 0, 0, 0};
  if (blockIdx.x == 8 && tid == 0) out[0] = 0.0f;

  const float4* zr = (const float4*)(z + (size_t)row * DIM);
  float4 v[4];
  #pragma unroll
  for (int j = 0; j < 4; j++) v[j] = zr[lane + 64 * j];
  float ss = 0.0f;
  #pragma unroll
  for (int j = 0; j < 4; j++)
    ss += v[j].x * v[j].x + v[j].y * v[j].y + v[j].z * v[j].z + v[j].w * v[j].w;
  #pragma unroll
  for (int off = 32; off > 0; off >>= 1) ss += __shfl_xor(ss, off);
  const float scale = rsqrtf(ss) * ROW_SCALE;  // norms ~32 >> eps

  unsigned* o = (unsigned*)(zn + (size_t)row * DIM);
  #pragma unroll
  for (int j = 0; j < 4; j++)
    o[lane + 64 * j] = pack4_e4m3(v[j].x * scale, v[j].y * scale,
                                  v[j].z * scale, v[j].w * scale);
}

// Supercell-major decode over the 32x32 supertile triangle: 4x4 supercells
// (8 cell-rows). Diag cell = 10 tiles (upper-tri 4x4), off-diag = 16.
// Prefix P(SI) = 130*SI - 8*SI*SI (P(8)=528). Within a row: diag cell
// first, then snake over off-diag cells; within cell row-major.
// (Verified correct in R20.)
__device__ __forceinline__ void decode_tile(int g, int& I, int& J) {
  int SI = 0;
  #pragma unroll
  for (int s = 1; s < 8; ++s)
    if (130 * s - 8 * s * s <= g) SI = s;
  int rem = g - (130 * SI - 8 * SI * SI);
  int i, j, SJ;
  if (rem < 10) {                       // diagonal supercell, upper-tri 4x4
    SJ = SI;
    i = 0;
    while ((i + 1) * (9 - (i + 1)) / 2 <= rem) ++i;  // prefix(i)=i*(9-i)/2
    j = i + (rem - i * (9 - i) / 2);
  } else {                              // full off-diagonal supercell
    const int rem2 = rem - 10;
    const int cc = rem2 >> 4;           // 0 .. (6-SI)
    const int k  = rem2 & 15;
    SJ = (SI & 1) ? (7 - cc) : (SI + 1 + cc);
    i = k >> 2;
    j = k & 3;
  }
  I = SI * 4 + i;
  J = SJ * 4 + j;
}

// ---------------- Kernel 2: upper-tri MX-fp8 GEMM + partial sum-exp -------
__global__ __launch_bounds__(512, 1) void fused_gemm_lse(
    const unsigned char* __restrict__ zn, float* __restrict__ sumexp,
    float* __restrict__ pos) {
  __shared__ unsigned char sA[2][BM * BK];    // 2 x 32 KB (double buffer)
  __shared__ unsigned char sB[2][BM * BK];    // 2 x 32 KB (double buffer)
  __shared__ float rowRed[2][BM];             // 2 KB
  __shared__ float colRed[4][BM];             // 4 KB   (total 134 KB)

  const int tid  = threadIdx.x;               // 0..511
  const int lane = tid & 63;
  const int wave = tid >> 6;                  // 0..7
  const int quad = lane >> 4;
  const int l15  = lane & 15;
  const int waveM = wave >> 1;  // 0..3  (64-row band)
  const int waveN = wave & 1;   // 0..1  (128-col half)

  // XCD-contiguous tile permutation (528 = 8 * 66)
  const int t = (blockIdx.x & 7) * (NTILES / 8) + (blockIdx.x >> 3);
  int I, J;
  decode_tile(t, I, J);
  const int rowBase = I * BM, colBase = J * BM;

  // staging: 256x128B tile = 2048 16B-chunks, 4/thread/matrix.
  // chunk s: row r = s>>3, stored slot s&7 holds logical 16B k-chunk
  // q = (s&7) ^ (r&7)  (XOR swizzle, applied on the global-address side).
  // LDS dest for chunk s is linear: s*16 = i*8192 + tid*16.
  int gOff[4];
  #pragma unroll
  for (int i = 0; i < 4; i++) {
    const int s = i * 512 + tid;            // 0..2047
    const int r = s >> 3;                   // tile row 0..255
    const int q = (s & 7) ^ (r & 7);        // logical k-chunk 0..7
    gOff[i] = r * DIM + q * 16;
  }
  const unsigned char* gA = zn + (size_t)rowBase * DIM;
  const unsigned char* gB = zn + (size_t)colBase * DIM;
  auto stage = [&](int buf, int p) {
    #pragma unroll
    for (int i = 0; i < 4; i++)
      async_copy16(gA + p * BK + gOff[i],
                   (char*)sA[buf] + i * 8192 + tid * 16);
    #pragma unroll
    for (int i = 0; i < 4; i++)
      async_copy16(gB + p * BK + gOff[i],
                   (char*)sB[buf] + i * 8192 + tid * 16);
  };

  floatx4 acc[4][8];
  #pragma unroll
  for (int mi = 0; mi < 4; mi++)
    #pragma unroll
    for (int ni = 0; ni < 8; ni++) acc[mi][ni] = {0.f, 0.f, 0.f, 0.f};

  // per-lane frag-read constants: row&7 == l15&7 for every frag row
  // (row = base + k*16, bases are multiples of 64) -> c0 is lane-constant.
  const int c0 = (quad * 2) ^ (l15 & 7);
  // A frag base: row rA0 = waveM*64 + l15, frag mi at +mi*16 rows
  const unsigned char* fA0;
  // B frag base: row rB0 = waveN*128 + l15, frag ni at +ni*16 rows
  const unsigned char* fB0;

  stage(0, 0);                          // only cold fill

  for (int p = 0; p < NPHASE; ++p) {
    const int b = p & 1;
    __syncthreads();                    // tile-p stage drained; prev reads done
    if (p + 1 < NPHASE) stage(b ^ 1, p + 1);   // async prefetch (other bufs)

    fA0 = &sA[b][((waveM * 64 + l15) * 8) * 16];
    fB0 = &sB[b][((waveN * 128 + l15) * 8) * 16];

    // hold A (4 frags = 32 regs), stream B (8 regs at a time)
    intx8 ah[4];
    #pragma unroll
    for (int mi = 0; mi < 4; mi++) {
      const intx4 lo = *(const intx4*)(fA0 + mi * 2048 + c0 * 16);
      const intx4 hi = *(const intx4*)(fA0 + mi * 2048 + (c0 ^ 1) * 16);
      ah[mi] = __builtin_shufflevector(lo, hi, 0, 1, 2, 3, 4, 5, 6, 7);
    }
    #pragma unroll
    for (int ni = 0; ni < 8; ni++) {
      const intx4 lo = *(const intx4*)(fB0 + ni * 2048 + c0 * 16);
      const intx4 hi = *(const intx4*)(fB0 + ni * 2048 + (c0 ^ 1) * 16);
      const intx8 bfrag = __builtin_shufflevector(lo, hi, 0, 1, 2, 3, 4, 5, 6, 7);
      #pragma unroll
      for (int mi = 0; mi < 4; mi++)
        acc[mi][ni] = __builtin_amdgcn_mfma_scale_f32_16x16x128_f8f6f4(
            ah[mi], bfrag, acc[mi][ni],
            0 /*cbsz: A=e4m3*/, 0 /*blgp: B=e4m3*/,
            0, SCALE1,   // opsel_a, scale_a = 1.0
            0, SCALE1);  // opsel_b, scale_b = 1.0
    }
  }

  // ---- epilogue ----
  // C/D layout (16x16 family): col = l15, row = quad*4 + reg
  // lrow = waveM*64 + mi*16 + quad*4 + r; lcol = waveN*128 + ni*16 + l15
  const bool diagBlk = (I == J);

  if (J == I + 16) {  // positive-pair supertile (col = row + 4096)
    #pragma unroll
    for (int mi = 0; mi < 4; mi++)
      #pragma unroll
      for (int ni = 0; ni < 8; ni++)
        #pragma unroll
        for (int r = 0; r < 4; r++) {
          const int lrow = waveM * 64 + mi * 16 + quad * 4 + r;
          const int lcol = waveN * 128 + ni * 16 + l15;
          if (lrow == lcol) pos[rowBase + lrow] = acc[mi][ni][r];
        }
  }

  float rsum[4][4], csum[8];
  #pragma unroll
  for (int mi = 0; mi < 4; mi++)
    #pragma unroll
    for (int r = 0; r < 4; r++) rsum[mi][r] = 0.0f;
  #pragma unroll
  for (int ni = 0; ni < 8; ni++) csum[ni] = 0.0f;

  if (diagBlk) {
    // full square; rsum only (lower half = mirrored col contributions);
    // mask the true diagonal.
    #pragma unroll
    for (int mi = 0; mi < 4; mi++)
      #pragma unroll
      for (int ni = 0; ni < 8; ni++)
        #pragma unroll
        for (int r = 0; r < 4; r++) {
          const int lrow = waveM * 64 + mi * 16 + quad * 4 + r;
          const int lcol = waveN * 128 + ni * 16 + l15;
          float e = exp2f(acc[mi][ni][r] - OFFS);
          if (lrow == lcol) e = 0.0f;         // masked diagonal
          rsum[mi][r] += e;
        }
  } else {
    #pragma unroll
    for (int mi = 0; mi < 4; mi++)
      #pragma unroll
      for (int ni = 0; ni < 8; ni++)
        #pragma unroll
        for (int r = 0; r < 4; r++) {
          const float e = exp2f(acc[mi][ni][r] - OFFS);
          rsum[mi][r] += e;
          csum[ni]    += e;
        }
  }

  // row sums: reduce over the 16 cols (l15) of each fragment row
  #pragma unroll
  for (int mi = 0; mi < 4; mi++)
    #pragma unroll
    for (int r = 0; r < 4; r++) {
      float v = rsum[mi][r];
      v += __shfl_xor(v, 1);
      v += __shfl_xor(v, 2);
      v += __shfl_xor(v, 4);
      v += __shfl_xor(v, 8);
      if (l15 == 0)
        rowRed[waveN][waveM * 64 + mi * 16 + quad * 4 + r] = v;
    }
  // col sums: fold the 4 quads; 4 row-bands (waveM) to combine later
  if (!diagBlk) {
    #pragma unroll
    for (int ni = 0; ni < 8; ni++) {
      float v = csum[ni];
      v += __shfl_xor(v, 16);
      v += __shfl_xor(v, 32);
      if (quad == 0)
        colRed[waveM][waveN * 128 + ni * 16 + l15] = v;
    }
  }
  __syncthreads();

  if (tid < BM) {
    atomicAdd(&sumexp[rowBase + tid], rowRed[0][tid] + rowRed[1][tid]);
  } else if (!diagBlk) {
    const int c = tid - BM;
    atomicAdd(&sumexp[colBase + c],
              colRed[0][c] + colRed[1][c] + colRed[2][c] + colRed[3][c]);
  }
}

// ---------------- Kernel 3: mean NLL --------------------------------------
__global__ __launch_bounds__(256) void finalize_kernel(
    const float* __restrict__ sumexp, const float* __restrict__ pos,
    float* __restrict__ out) {
  const int tid = threadIdx.x;
  const int row = blockIdx.x * 256 + tid;
  // pos holds d = logit*log2e for rows [0,4096); pos[i+4096] == pos[i]
  float local = -(pos[row & (N_ROWS / 2 - 1)] * LN2) + LOGIT_MAX + logf(sumexp[row]);
  #pragma unroll
  for (int off = 32; off > 0; off >>= 1) local += __shfl_xor(local, off);
  __shared__ float red[4];
  const int wave = tid >> 6, lane = tid & 63;
  if (lane == 0) red[wave] = local;
  __syncthreads();
  if (tid == 0)
    atomicAdd(out, (red[0] + red[1] + red[2] + red[3]) * (1.0f / N_ROWS));
}

extern "C" void kernel_launch(void* const* d_in, const int* in_sizes, int n_in,
                              void* d_out, int out_size, void* d_ws, size_t ws_size,
                              hipStream_t stream) {
  const float* z = (const float*)d_in[0];
  float* out = (float*)d_out;

  char* ws = (char*)d_ws;
  unsigned char* zn = (unsigned char*)ws;                    // 8 MB fp8
  float* sumexp = (float*)(ws + (size_t)N_ROWS * DIM);       // 32 KB
  float* pos    = sumexp + N_ROWS;                           // 16 KB

  normalize_kernel<<<N_ROWS / 4, 256, 0, stream>>>(z, zn, sumexp, out);
  fused_gemm_lse<<<NTILES, 512, 0, stream>>>(zn, sumexp, pos);
  finalize_kernel<<<N_ROWS / 256, 256, 0, stream>>>(sumexp, pos, out);
}